// Round 5
// baseline (349.753 us; speedup 1.0000x reference)
//
#include <hip/hip_runtime.h>

// AttributeDecoder: out[k,s,:] = feats[mask_idx[k,s],:] @ W[k] + b[k]. fp32.
// R7: INVERTED dense-GEMM restructure. R2-R6 ledger: gather-per-(k,s) engine
// pinned at ~84us (~5 TB/s gather service) invariant to VALU cuts, HBM
// locality, and pipeline depth => abandon gather structure.
// New: stream feats densely ONCE (134MB coalesced, 64-row tiles), compute all
// 24 heads per row via bf16-split MFMA (fp32-accurate: Ahi*Bhi+Alo*Bhi+Ahi*Blo),
// heads paired to fill N=16. Scatter referenced (k,s) via row-bucketed inverted
// index (64-row granularity). Prep kernels: W bf16-split + zero, 2048-bin
// histogram, scan, entry scatter. Fallback to verified R3 kernel if ws small.

#define KH 24
#define SS 16384
#define VV 8
#define DD 256
#define NROW 131072
#define NE (KH * SS)        // 393216 entries
#define NB 2048             // 64-row blocks
#define LDSP 196            // padded C-tile row stride (floats)

typedef __attribute__((ext_vector_type(8))) short s16x8;
typedef __attribute__((ext_vector_type(4))) float f32x4;

__device__ __forceinline__ unsigned short rne_bf16(float f) {
    unsigned u = __builtin_bit_cast(unsigned, f);
    unsigned r = u + 0x7FFFu + ((u >> 16) & 1u);
    return (unsigned short)(r >> 16);
}
__device__ __forceinline__ float bf16f(unsigned short h) {
    unsigned u = ((unsigned)h) << 16;
    return __builtin_bit_cast(float, u);
}

template <int CTRL>
__device__ __forceinline__ float dpp_mov(float x) {
    int xi = __builtin_bit_cast(int, x);
    int r = __builtin_amdgcn_update_dpp(xi, xi, CTRL, 0xF, 0xF, false);
    return __builtin_bit_cast(float, r);
}

// ---- wk: split W into bf16 hi/lo in MFMA B-fragment order; zero cursor ----
// whi/wlo layout: [((hp*8+kb)*64 + lane)*8 + j] = B-elem for
//   k = kb*32 + (lane>>4)*8 + j, n = lane&15 (head = hp*2+(n>>3), v = n&7)
__global__ __launch_bounds__(256) void wk_kernel(
    const float* __restrict__ head_w, unsigned short* __restrict__ whi,
    unsigned short* __restrict__ wlo, unsigned* __restrict__ cursor)
{
    const int idx = blockIdx.x * 256 + threadIdx.x;     // 0..49151
    if (idx < NB) cursor[idx] = 0u;
    const int j = idx & 7, lane = (idx >> 3) & 63;
    const int kb = (idx >> 9) & 7, hp = idx >> 12;
    const int head = hp * 2 + ((lane & 15) >> 3);
    const int v = lane & 7;
    const int k = kb * 32 + (lane >> 4) * 8 + j;
    const float f = head_w[((size_t)head * DD + k) * VV + v];
    const unsigned short hi = rne_bf16(f);
    whi[idx] = hi;
    wlo[idx] = rne_bf16(f - bf16f(hi));
}

// ---- hk: histogram of rows into 2048 64-row bins ----
__global__ __launch_bounds__(256) void hk_kernel(
    const int* __restrict__ mask_idx, unsigned* __restrict__ cursor)
{
    const int idx = blockIdx.x * 256 + threadIdx.x;
    const unsigned row = (unsigned)mask_idx[idx];
    atomicAdd(&cursor[row >> 6], 1u);
}

// ---- sk: exclusive scan of 2048 bins -> bbounds + running cursor ----
__global__ __launch_bounds__(1024) void sk_kernel(
    unsigned* __restrict__ cursor, int* __restrict__ bbounds)
{
    const int tid = threadIdx.x;
    __shared__ unsigned part[1024];
    const unsigned c0 = cursor[2 * tid], c1 = cursor[2 * tid + 1];
    part[tid] = c0 + c1;
    __syncthreads();
    for (int off = 1; off < 1024; off <<= 1) {
        unsigned v = (tid >= off) ? part[tid - off] : 0u;
        __syncthreads();
        part[tid] += v;
        __syncthreads();
    }
    const unsigned ex = tid ? part[tid - 1] : 0u;
    bbounds[2 * tid] = (int)ex;
    bbounds[2 * tid + 1] = (int)(ex + c0);
    cursor[2 * tid] = ex;
    cursor[2 * tid + 1] = ex + c0;
    if (tid == 0) bbounds[NB] = NE;
}

// ---- ek: scatter packed entries ((row&63)<<19 | k<<14 | s) into buckets ----
__global__ __launch_bounds__(256) void ek_kernel(
    const int* __restrict__ mask_idx, unsigned* __restrict__ cursor,
    unsigned* __restrict__ entries)
{
    const int idx = blockIdx.x * 256 + threadIdx.x;     // idx = k*16384+s < 2^19
    const unsigned row = (unsigned)mask_idx[idx];
    const unsigned pos = atomicAdd(&cursor[row >> 6], 1u);
    entries[pos] = ((row & 63u) << 19) | (unsigned)idx;
}

// ---- mk: dense 64-row tile: split-bf16 MFMA over 12 head-pairs + scatter ----
__global__ __launch_bounds__(256) void mk_kernel(
    const float* __restrict__ feats,
    const unsigned short* __restrict__ whi,
    const unsigned short* __restrict__ wlo,
    const unsigned* __restrict__ entries,
    const int* __restrict__ bbounds,
    const float* __restrict__ head_b,
    float* __restrict__ out)
{
    const int tid  = threadIdx.x;
    const int wave = tid >> 6;
    const int lane = tid & 63;
    const int m    = lane & 15;          // A row within 16-row subtile
    const int kq   = lane >> 4;          // k-group (A/B) and row-group (C)
    const int r0   = blockIdx.x * 64;

    __shared__ float Cl[64 * LDSP];      // 49KB: C tile 64 x 192 (padded)
    __shared__ unsigned short Bbuf[8192];// 16KB: one head-pair's Whi|Wlo frags
    __shared__ float bias_s[192];
    if (tid < 192) bias_s[tid] = head_b[tid];

    // Stage A: rows r0 + wave*16 + m, all K=256, split to bf16 hi/lo frags.
    const float* arow = feats + ((size_t)(r0 + wave * 16 + m)) * DD + kq * 8;
    s16x8 ahi[8], alo[8];
#pragma unroll
    for (int kb = 0; kb < 8; ++kb) {
        const float4 p = *(const float4*)(arow + kb * 32);
        const float4 q = *(const float4*)(arow + kb * 32 + 4);
        const float fv[8] = {p.x, p.y, p.z, p.w, q.x, q.y, q.z, q.w};
#pragma unroll
        for (int j = 0; j < 8; ++j) {
            const unsigned short hi = rne_bf16(fv[j]);
            ahi[kb][j] = (short)hi;
            alo[kb][j] = (short)rne_bf16(fv[j] - bf16f(hi));
        }
    }

    for (int hp = 0; hp < 12; ++hp) {
        if (hp) __syncthreads();         // prev Bbuf readers done
        {   // cooperative copy: whi[hp] (8KB) -> Bbuf[0:], wlo[hp] -> Bbuf[4096:]
            const uint4* sh = (const uint4*)(whi + hp * 4096);
            const uint4* sl = (const uint4*)(wlo + hp * 4096);
            uint4* bb = (uint4*)Bbuf;
            bb[tid]       = sh[tid];
            bb[256 + tid] = sh[256 + tid];
            bb[512 + tid] = sl[tid];
            bb[768 + tid] = sl[256 + tid];
        }
        __syncthreads();

        f32x4 c = {0.f, 0.f, 0.f, 0.f};
#pragma unroll
        for (int kb = 0; kb < 8; ++kb) {
            const s16x8 bh = *(const s16x8*)((const char*)Bbuf + kb * 1024 + lane * 16);
            const s16x8 bl = *(const s16x8*)((const char*)Bbuf + 8192 + kb * 1024 + lane * 16);
            c = __builtin_amdgcn_mfma_f32_16x16x32_bf16(ahi[kb], bh, c, 0, 0, 0);
            c = __builtin_amdgcn_mfma_f32_16x16x32_bf16(alo[kb], bh, c, 0, 0, 0);
            c = __builtin_amdgcn_mfma_f32_16x16x32_bf16(ahi[kb], bl, c, 0, 0, 0);
        }
        // D[row=(lane>>4)*4+reg][col=lane&15]; global col = hp*16 + (lane&15)
#pragma unroll
        for (int rg = 0; rg < 4; ++rg)
            Cl[(wave * 16 + kq * 4 + rg) * LDSP + hp * 16 + (lane & 15)] = c[rg];
    }
    __syncthreads();

    // Scatter referenced entries: 8 lanes per entry (v = tid&7).
    const int lo_e = bbounds[blockIdx.x];
    const int hi_e = bbounds[blockIdx.x + 1];
    const int v = tid & 7;
    for (int e = lo_e + (tid >> 3); e < hi_e; e += 32) {
        const unsigned ent = entries[e];
        const int nl = (int)(ent >> 19);
        const int kk = (int)((ent >> 14) & 31u);
        const int s  = (int)(ent & 16383u);
        const float val = Cl[nl * LDSP + kk * 8 + v] + bias_s[kk * 8 + v];
        out[((size_t)kk * SS + s) * VV + v] = val;
    }
}

// ---------------- Fallback (verified R3) if workspace too small ------------
__global__ __launch_bounds__(256) void attr_decoder_fallback(
    const float* __restrict__ feats, const int* __restrict__ mask_idx,
    const float* __restrict__ head_w, const float* __restrict__ head_b,
    float* __restrict__ out)
{
    const int lane  = threadIdx.x & 63;
    const int wv    = __builtin_amdgcn_readfirstlane(threadIdx.x >> 6);
    const int k     = blockIdx.x >> 7;
    const int chunk = blockIdx.x & 127;
    const int lb    = lane & 7;

    const float* Wk = head_w + (size_t)k * (DD * VV);
    float w[4][8];
    {
        const bool q0 = (lane & 1) != 0;
        const bool q1 = (lane & 2) != 0;
        const bool q2 = (lane & 4) != 0;
#pragma unroll
        for (int t = 0; t < 4; ++t) {
            const float4 a = *(const float4*)(Wk + (lane * 4 + t) * VV);
            const float4 b = *(const float4*)(Wk + (lane * 4 + t) * VV + 4);
            const float x[8] = {a.x, a.y, a.z, a.w, b.x, b.y, b.z, b.w};
            float y[8], z[8];
#pragma unroll
            for (int j = 0; j < 8; ++j) y[j] = q0 ? x[j ^ 1] : x[j];
#pragma unroll
            for (int j = 0; j < 8; ++j) z[j] = q1 ? y[j ^ 2] : y[j];
#pragma unroll
            for (int j = 0; j < 8; ++j) w[t][j] = q2 ? z[j ^ 4] : z[j];
        }
    }
    const float bias = head_b[k * VV + lb];

    const char* fb = (const char*)feats;
    const int s_base = chunk * 128 + wv * 32;
    const int* mi = mask_idx + k * SS + s_base;
    float* outp = out + ((size_t)k * SS + s_base) * VV;
    const int vo = lane << 4;

    int4 rows = *(const int4*)mi;
    int r0 = __builtin_amdgcn_readfirstlane(rows.x);
    int r1 = __builtin_amdgcn_readfirstlane(rows.y);
    int r2 = __builtin_amdgcn_readfirstlane(rows.z);
    int r3 = __builtin_amdgcn_readfirstlane(rows.w);

    for (int i = 0; i < 32; i += 4) {
        const float4 f0 = *(const float4*)(fb + (((size_t)(unsigned)r0) << 10) + vo);
        const float4 f1 = *(const float4*)(fb + (((size_t)(unsigned)r1) << 10) + vo);
        const float4 f2 = *(const float4*)(fb + (((size_t)(unsigned)r2) << 10) + vo);
        const float4 f3 = *(const float4*)(fb + (((size_t)(unsigned)r3) << 10) + vo);
        if (i < 28) rows = *(const int4*)(mi + i + 4);

        float r[4];
        const float4 f[4] = {f0, f1, f2, f3};
#pragma unroll
        for (int u = 0; u < 4; ++u) {
            float acc[8];
#pragma unroll
            for (int v = 0; v < 8; ++v) {
                acc[v] = f[u].x * w[0][v];
                acc[v] = fmaf(f[u].y, w[1][v], acc[v]);
                acc[v] = fmaf(f[u].z, w[2][v], acc[v]);
                acc[v] = fmaf(f[u].w, w[3][v], acc[v]);
            }
            const float a40 = acc[0] + dpp_mov<0xB1>(acc[1]);
            const float a41 = acc[2] + dpp_mov<0xB1>(acc[3]);
            const float a42 = acc[4] + dpp_mov<0xB1>(acc[5]);
            const float a43 = acc[6] + dpp_mov<0xB1>(acc[7]);
            const float a20 = a40 + dpp_mov<0x4E>(a41);
            const float a21 = a42 + dpp_mov<0x4E>(a43);
            r[u] = a20 + __shfl_xor(a21, 4, 64);
        }
        r0 = __builtin_amdgcn_readfirstlane(rows.x);
        r1 = __builtin_amdgcn_readfirstlane(rows.y);
        r2 = __builtin_amdgcn_readfirstlane(rows.z);
        r3 = __builtin_amdgcn_readfirstlane(rows.w);

        const bool b3 = (lane & 8) != 0;
        const bool b4 = (lane & 16) != 0;
        const float t0 = (b3 ? r[1] : r[0]) + dpp_mov<0x128>(b3 ? r[0] : r[1]);
        const float t1 = (b3 ? r[3] : r[2]) + dpp_mov<0x128>(b3 ? r[2] : r[3]);
        float va = (b4 ? t1 : t0) + __shfl_xor(b4 ? t0 : t1, 16, 64);
        va += __shfl_xor(va, 32, 64);
        if (lane < 32) outp[i * VV + lane] = va + bias;
    }
}

extern "C" void kernel_launch(void* const* d_in, const int* in_sizes, int n_in,
                              void* d_out, int out_size, void* d_ws, size_t ws_size,
                              hipStream_t stream) {
    const float* feats    = (const float*)d_in[1];
    const int*   mask_idx = (const int*)  d_in[2];
    const float* head_w   = (const float*)d_in[3];
    const float* head_b   = (const float*)d_in[4];
    float* out = (float*)d_out;

    // Workspace layout (bytes):
    //   cursor  @ 0        : 2048 * 4      = 8192
    //   bbounds @ 8192     : 2049 * 4      = 8196  (pad to 16400)
    //   entries @ 16400    : 393216 * 4    = 1572864
    //   whi     @ 1589264  : 98304 * 2     = 196608
    //   wlo     @ 1785872  : 98304 * 2     = 196608   -> need 1982480
    const size_t need = 1982480;
    if (d_ws != nullptr && ws_size >= need) {
        char* ws = (char*)d_ws;
        unsigned* cursor  = (unsigned*)(ws);
        int* bbounds      = (int*)(ws + 8192);
        unsigned* entries = (unsigned*)(ws + 16400);
        unsigned short* whi = (unsigned short*)(ws + 1589264);
        unsigned short* wlo = (unsigned short*)(ws + 1785872);

        wk_kernel<<<dim3(192),  dim3(256),  0, stream>>>(head_w, whi, wlo, cursor);
        hk_kernel<<<dim3(1536), dim3(256),  0, stream>>>(mask_idx, cursor);
        sk_kernel<<<dim3(1),    dim3(1024), 0, stream>>>(cursor, bbounds);
        ek_kernel<<<dim3(1536), dim3(256),  0, stream>>>(mask_idx, cursor, entries);
        mk_kernel<<<dim3(NB),   dim3(256),  0, stream>>>(
            feats, whi, wlo, entries, bbounds, head_b, out);
    } else {
        attr_decoder_fallback<<<dim3(KH * 128), dim3(256), 0, stream>>>(
            feats, mask_idx, head_w, head_b, out);
    }
}

// Round 6
// 249.884 us; speedup vs baseline: 1.3997x; 1.3997x over previous
//
#include <hip/hip_runtime.h>

// AttributeDecoder: out[k,s,:] = feats[mask_idx[k,s],:] @ W[k] + b[k]. fp32.
// R8: dense-GEMM + dense-logits + trivial gather.
//  R7 post-mortem: inverted GEMM worked (MfmaUtil 15%) but was strangled by
//  49KB C-tile LDS (2 blocks/CU), 24 barriers/block, LDS-scatter conflicts,
//  and 5-kernel index prep. R8:
//   wk : split W -> bf16 hi/lo in MFMA B-frag order (layout verified in R7)
//   mkd: 2048 blocks x 64 rows: stream feats once (coalesced), split-bf16
//        MFMA (Ahi*Bhi+Alo*Bhi+Ahi*Blo, fp32-accurate), D straight to global
//        logits[hp][row][16] (64B cells). LDS = 2x16KB dbuf B only ->
//        5 blocks/CU; 1 barrier per head-pair; B prefetch under compute.
//   gk : out[t] = logits[(hp*N+row)*16 + (k&1)*8 + v] + bias -- one aligned
//        32B read in one 64B line, out writes perfectly coalesced (idx==tid).
// Fallback to verified R3 gather kernel if workspace < ~101MB.

#define KH 24
#define SS 16384
#define VV 8
#define DD 256
#define NROW 131072
#define NE (KH * SS)

typedef __attribute__((ext_vector_type(8))) short s16x8;
typedef __attribute__((ext_vector_type(4))) float f32x4;

__device__ __forceinline__ unsigned short rne_bf16(float f) {
    unsigned u = __builtin_bit_cast(unsigned, f);
    unsigned r = u + 0x7FFFu + ((u >> 16) & 1u);
    return (unsigned short)(r >> 16);
}
__device__ __forceinline__ float bf16f(unsigned short h) {
    unsigned u = ((unsigned)h) << 16;
    return __builtin_bit_cast(float, u);
}

template <int CTRL>
__device__ __forceinline__ float dpp_mov(float x) {
    int xi = __builtin_bit_cast(int, x);
    int r = __builtin_amdgcn_update_dpp(xi, xi, CTRL, 0xF, 0xF, false);
    return __builtin_bit_cast(float, r);
}

// ---- wk: split W into bf16 hi/lo in MFMA B-fragment order (R7-verified) ----
// whi/wlo[((hp*8+kb)*64+lane)*8+j]: k = kb*32+(lane>>4)*8+j, n = lane&15,
// head = hp*2+(n>>3), v = n&7.
__global__ __launch_bounds__(256) void wk_kernel(
    const float* __restrict__ head_w, unsigned short* __restrict__ whi,
    unsigned short* __restrict__ wlo)
{
    const int idx = blockIdx.x * 256 + threadIdx.x;     // 0..49151
    const int j = idx & 7, lane = (idx >> 3) & 63;
    const int kb = (idx >> 9) & 7, hp = idx >> 12;
    const int head = hp * 2 + ((lane & 15) >> 3);
    const int v = lane & 7;
    const int k = kb * 32 + (lane >> 4) * 8 + j;
    const float f = head_w[((size_t)head * DD + k) * VV + v];
    const unsigned short hi = rne_bf16(f);
    whi[idx] = hi;
    wlo[idx] = rne_bf16(f - bf16f(hi));
}

// ---- mkd: dense 64-row tile -> logits[hp][row][16], no C staging ----------
__global__ __launch_bounds__(256) void mkd_kernel(
    const float* __restrict__ feats,
    const unsigned short* __restrict__ whi,
    const unsigned short* __restrict__ wlo,
    float* __restrict__ logits)
{
    const int tid  = threadIdx.x;
    const int wave = tid >> 6;
    const int lane = tid & 63;
    const int m    = lane & 15;          // A row within 16-row subtile; D col
    const int kq   = lane >> 4;
    const int r0   = blockIdx.x * 64;

    __shared__ unsigned short Bbuf[2][8192];   // 2 x (8KB hi | 8KB lo)

    // Stage A: rows r0 + wave*16 + m, K=256 -> bf16 hi/lo frags (R7-verified).
    const float* arow = feats + ((size_t)(r0 + wave * 16 + m)) * DD + kq * 8;
    s16x8 ahi[8], alo[8];
#pragma unroll
    for (int kb = 0; kb < 8; ++kb) {
        const float4 p = *(const float4*)(arow + kb * 32);
        const float4 q = *(const float4*)(arow + kb * 32 + 4);
        const float fv[8] = {p.x, p.y, p.z, p.w, q.x, q.y, q.z, q.w};
#pragma unroll
        for (int j = 0; j < 8; ++j) {
            const unsigned short hi = rne_bf16(fv[j]);
            ahi[kb][j] = (short)hi;
            alo[kb][j] = (short)rne_bf16(fv[j] - bf16f(hi));
        }
    }

    // Prologue: stage hp=0 into buf0.
    {
        const uint4* sh = (const uint4*)(whi);
        const uint4* sl = (const uint4*)(wlo);
        uint4* bb = (uint4*)(&Bbuf[0][0]);
        bb[tid]       = sh[tid];
        bb[256 + tid] = sh[256 + tid];
        bb[512 + tid] = sl[tid];
        bb[768 + tid] = sl[256 + tid];
    }
    __syncthreads();

    for (int hp = 0; hp < 12; ++hp) {
        const int cur = hp & 1;

        // Issue next head-pair's B loads (land during compute; T14 split).
        uint4 t0, t1, t2, t3;
        const bool pf = (hp + 1) < 12;
        if (pf) {
            const uint4* sh = (const uint4*)(whi + (hp + 1) * 4096);
            const uint4* sl = (const uint4*)(wlo + (hp + 1) * 4096);
            t0 = sh[tid]; t1 = sh[256 + tid];
            t2 = sl[tid]; t3 = sl[256 + tid];
        }

        f32x4 c = {0.f, 0.f, 0.f, 0.f};
#pragma unroll
        for (int kb = 0; kb < 8; ++kb) {
            const s16x8 bh = *(const s16x8*)(&Bbuf[cur][kb * 512 + lane * 8]);
            const s16x8 bl = *(const s16x8*)(&Bbuf[cur][4096 + kb * 512 + lane * 8]);
            c = __builtin_amdgcn_mfma_f32_16x16x32_bf16(ahi[kb], bh, c, 0, 0, 0);
            c = __builtin_amdgcn_mfma_f32_16x16x32_bf16(alo[kb], bh, c, 0, 0, 0);
            c = __builtin_amdgcn_mfma_f32_16x16x32_bf16(ahi[kb], bl, c, 0, 0, 0);
        }

        // D[row=kq*4+rg][col=m] -> logits[hp][r0+wave*16+kq*4+rg][m]
        float* Lp = logits + ((size_t)hp * NROW + (r0 + wave * 16 + kq * 4)) * 16 + m;
#pragma unroll
        for (int rg = 0; rg < 4; ++rg)
            Lp[(size_t)rg * 16] = c[rg];

        if (pf) {
            uint4* bb = (uint4*)(&Bbuf[cur ^ 1][0]);
            bb[tid]       = t0;
            bb[256 + tid] = t1;
            bb[512 + tid] = t2;
            bb[768 + tid] = t3;
            __syncthreads();
        }
    }
}

// ---- gk: out[t] = logits[(hp*NROW+row)*16 + half*8 + v] + bias ------------
__global__ __launch_bounds__(256) void gk_kernel(
    const float* __restrict__ logits,
    const int* __restrict__ mask_idx,
    const float* __restrict__ head_b,
    float* __restrict__ out)
{
    const int t = blockIdx.x * 256 + threadIdx.x;       // 0 .. NE*8-1
    const int e = t >> 3;                               // (k,s) entry
    const int v = t & 7;
    const int k = e >> 14;
    const unsigned row = (unsigned)mask_idx[e];
    const int hp = k >> 1, half = k & 1;
    out[t] = logits[((size_t)hp * NROW + row) * 16 + half * 8 + v]
           + head_b[k * VV + v];
}

// ---------------- Fallback (verified R3) if workspace too small ------------
__global__ __launch_bounds__(256) void attr_decoder_fallback(
    const float* __restrict__ feats, const int* __restrict__ mask_idx,
    const float* __restrict__ head_w, const float* __restrict__ head_b,
    float* __restrict__ out)
{
    const int lane  = threadIdx.x & 63;
    const int wv    = __builtin_amdgcn_readfirstlane(threadIdx.x >> 6);
    const int k     = blockIdx.x >> 7;
    const int chunk = blockIdx.x & 127;
    const int lb    = lane & 7;

    const float* Wk = head_w + (size_t)k * (DD * VV);
    float w[4][8];
    {
        const bool q0 = (lane & 1) != 0;
        const bool q1 = (lane & 2) != 0;
        const bool q2 = (lane & 4) != 0;
#pragma unroll
        for (int t = 0; t < 4; ++t) {
            const float4 a = *(const float4*)(Wk + (lane * 4 + t) * VV);
            const float4 b = *(const float4*)(Wk + (lane * 4 + t) * VV + 4);
            const float x[8] = {a.x, a.y, a.z, a.w, b.x, b.y, b.z, b.w};
            float y[8], z[8];
#pragma unroll
            for (int j = 0; j < 8; ++j) y[j] = q0 ? x[j ^ 1] : x[j];
#pragma unroll
            for (int j = 0; j < 8; ++j) z[j] = q1 ? y[j ^ 2] : y[j];
#pragma unroll
            for (int j = 0; j < 8; ++j) w[t][j] = q2 ? z[j ^ 4] : z[j];
        }
    }
    const float bias = head_b[k * VV + lb];

    const char* fb = (const char*)feats;
    const int s_base = chunk * 128 + wv * 32;
    const int* mi = mask_idx + k * SS + s_base;
    float* outp = out + ((size_t)k * SS + s_base) * VV;
    const int vo = lane << 4;

    int4 rows = *(const int4*)mi;
    int r0 = __builtin_amdgcn_readfirstlane(rows.x);
    int r1 = __builtin_amdgcn_readfirstlane(rows.y);
    int r2 = __builtin_amdgcn_readfirstlane(rows.z);
    int r3 = __builtin_amdgcn_readfirstlane(rows.w);

    for (int i = 0; i < 32; i += 4) {
        const float4 f0 = *(const float4*)(fb + (((size_t)(unsigned)r0) << 10) + vo);
        const float4 f1 = *(const float4*)(fb + (((size_t)(unsigned)r1) << 10) + vo);
        const float4 f2 = *(const float4*)(fb + (((size_t)(unsigned)r2) << 10) + vo);
        const float4 f3 = *(const float4*)(fb + (((size_t)(unsigned)r3) << 10) + vo);
        if (i < 28) rows = *(const int4*)(mi + i + 4);

        float r[4];
        const float4 f[4] = {f0, f1, f2, f3};
#pragma unroll
        for (int u = 0; u < 4; ++u) {
            float acc[8];
#pragma unroll
            for (int v = 0; v < 8; ++v) {
                acc[v] = f[u].x * w[0][v];
                acc[v] = fmaf(f[u].y, w[1][v], acc[v]);
                acc[v] = fmaf(f[u].z, w[2][v], acc[v]);
                acc[v] = fmaf(f[u].w, w[3][v], acc[v]);
            }
            const float a40 = acc[0] + dpp_mov<0xB1>(acc[1]);
            const float a41 = acc[2] + dpp_mov<0xB1>(acc[3]);
            const float a42 = acc[4] + dpp_mov<0xB1>(acc[5]);
            const float a43 = acc[6] + dpp_mov<0xB1>(acc[7]);
            const float a20 = a40 + dpp_mov<0x4E>(a41);
            const float a21 = a42 + dpp_mov<0x4E>(a43);
            r[u] = a20 + __shfl_xor(a21, 4, 64);
        }
        r0 = __builtin_amdgcn_readfirstlane(rows.x);
        r1 = __builtin_amdgcn_readfirstlane(rows.y);
        r2 = __builtin_amdgcn_readfirstlane(rows.z);
        r3 = __builtin_amdgcn_readfirstlane(rows.w);

        const bool b3 = (lane & 8) != 0;
        const bool b4 = (lane & 16) != 0;
        const float t0 = (b3 ? r[1] : r[0]) + dpp_mov<0x128>(b3 ? r[0] : r[1]);
        const float t1 = (b3 ? r[3] : r[2]) + dpp_mov<0x128>(b3 ? r[2] : r[3]);
        float va = (b4 ? t1 : t0) + __shfl_xor(b4 ? t0 : t1, 16, 64);
        va += __shfl_xor(va, 32, 64);
        if (lane < 32) outp[i * VV + lane] = va + bias;
    }
}

extern "C" void kernel_launch(void* const* d_in, const int* in_sizes, int n_in,
                              void* d_out, int out_size, void* d_ws, size_t ws_size,
                              hipStream_t stream) {
    const float* feats    = (const float*)d_in[1];
    const int*   mask_idx = (const int*)  d_in[2];
    const float* head_w   = (const float*)d_in[3];
    const float* head_b   = (const float*)d_in[4];
    float* out = (float*)d_out;

    // Workspace layout (bytes):
    //   logits @ 0         : 12*131072*16*4 = 100663296
    //   whi    @ 100663296 : 49152*2        = 98304 ... (= 12*8*64*8 shorts)
    //   wlo    @ 100761600 : 98304
    const size_t need = 100663296u + 2u * 98304u;
    if (d_ws != nullptr && ws_size >= need) {
        char* ws = (char*)d_ws;
        float* logits = (float*)ws;
        unsigned short* whi = (unsigned short*)(ws + 100663296u);
        unsigned short* wlo = (unsigned short*)(ws + 100761600u);

        wk_kernel<<<dim3(192),   dim3(256), 0, stream>>>(head_w, whi, wlo);
        mkd_kernel<<<dim3(2048), dim3(256), 0, stream>>>(feats, whi, wlo, logits);
        gk_kernel<<<dim3(NE * VV / 256), dim3(256), 0, stream>>>(
            logits, mask_idx, head_b, out);
    } else {
        attr_decoder_fallback<<<dim3(KH * 128), dim3(256), 0, stream>>>(
            feats, mask_idx, head_w, head_b, out);
    }
}